// Round 6
// baseline (422.035 us; speedup 1.0000x reference)
//
#include <hip/hip_runtime.h>

// Problem constants (from reference)
#define B_   16
#define OC_  10
#define N_   256
#define O_   2560   // OC_*N_
#define S_   64     // synapses
#define T_   512
#define KS_  48
#define TP_  561    // T + KS + 1
#define TT   24     // (fallback conv) time steps per thread
#define WROW 72     // (fallback conv) LDS row stride

// GEMM path constants
#define KTOT  3072          // S_*KS_
#define MPAD  9024          // 47*192 (B_*TP_=8976 padded to 192-multiple)
#define MVAL  8976
#define NB    40            // o-blocks of 64
#define BROWS (NB*192)      // 7680 Bt rows: (o>>5)*96 + d*32 + (o&31)

using i32x4 = __attribute__((ext_vector_type(4))) int;

// ===========================================================================
// prep_A8: im2col of x -> A[bt][k] int8 in {0,1}, k = i*48+j, packed 4/thread.
// Chunk-swizzled storage: within each 64-B K-block, 16-B chunk p is stored at
// position p ^ ((bt>>1)&3) -> conflict-free ds_read_b128 in the gemm.
// ===========================================================================
__global__ void prep_A8(const float* __restrict__ x, unsigned char* __restrict__ A) {
    int idx = blockIdx.x * 256 + threadIdx.x;
    if (idx >= MPAD * KTOT / 4) return;
    int bt = idx / (KTOT / 4);
    int k4 = (idx - bt * (KTOT / 4)) * 4;
    int b = bt / TP_, t = bt - b * TP_;
    unsigned v = 0;
    if (bt < MVAL) {
#pragma unroll
        for (int e = 0; e < 4; ++e) {
            int k = k4 + e;
            int i = k / KS_, j = k - i * KS_;
            int ts = t - 1 - j;
            unsigned bit = 0;
            if (ts >= 0 && ts < T_) bit = (x[((b << 6) + i) * T_ + ts] != 0.0f) ? 1u : 0u;
            v |= bit << (8 * e);
        }
    }
    int s = (bt >> 1) & 3;
    int p = (k4 >> 4) & 3;
    size_t baddr = (size_t)bt * KTOT + (k4 & ~63) + ((p ^ s) << 4) + (k4 & 15);
    *(unsigned*)(A + baddr) = v;
}

// ===========================================================================
// prep_B8: taps -> 22-bit fixed point -> three signed base-256 digits (i8).
// Row layout: n" = (o>>5)*96 + d*32 + (o&31); same chunk swizzle, key
// ((o&31)>>1)&3 (identical for all 3 digit rows since 32|d-offset).
// ===========================================================================
__global__ void prep_B8(const float* __restrict__ w, signed char* __restrict__ Bt) {
    int idx = blockIdx.x * 256 + threadIdx.x;  // o*3072 + k
    if (idx >= O_ * KTOT) return;
    int o = idx / KTOT;
    int k = idx - o * KTOT;
    int i = k / KS_, j = k - i * KS_;
    float wv = w[(o << 6) + i];
    float rise = (float)j * 0.0625f;
    float leak = -((float)j - wv * 16.0f) * 0.03125f + wv;
    float kv   = fmaxf(0.0f, fminf(rise, leak));     // in [0,1]
    int q  = (int)lrintf(kv * 4194304.0f);           // kv * 2^22
    int d0 = ((q + 128) & 255) - 128;                // [-128,127]
    int q1 = (q - d0) >> 8;
    int d1 = ((q1 + 128) & 255) - 128;               // [-128,127]
    int d2 = (q1 - d1) >> 8;                         // [0,64]
    int s   = (o >> 1) & 3;                          // == ((o&31)>>1)&3
    int ksw = (k & ~63) | ((((k >> 4) & 3) ^ s) << 4) | (k & 15);
    size_t base = ((size_t)(o >> 5) * 96 + (o & 31)) * KTOT + ksw;
    Bt[base]                      = (signed char)d0;
    Bt[base + (size_t)32 * KTOT]  = (signed char)d1;
    Bt[base + (size_t)64 * KTOT]  = (signed char)d2;
}

// ===========================================================================
// gemm_i8: block = 192 bt x 192 n-rows (64 o x 3 digits), 4 waves of 96x96,
// 6x6 frags.  DOUBLE-BUFFERED LDS: prefetch tile k+1 while computing tile k,
// so the vmcnt(0) drain before s_barrier lands AFTER the MFMA phase.
// mfma_i32_16x16x64_i8, exact int32 accumulation.
// ===========================================================================
__global__ __launch_bounds__(256, 2) void gemm_i8(
    const unsigned char* __restrict__ A,  // [MPAD][KTOT] in {0,1}, swizzled
    const signed char*  __restrict__ Bt,  // [BROWS][KTOT], swizzled
    float* __restrict__ pot)              // [MVAL][O_]
{
    __shared__ __align__(16) signed char Ash[2][192][64];
    __shared__ __align__(16) signed char Bsh[2][192][64];

    const int tid  = threadIdx.x;
    const int lane = tid & 63;
    const int wave = tid >> 6;
    const int row0  = blockIdx.y * 192;    // bt base (multiple of 192)
    const int ob    = blockIdx.x;          // o-block (64 outputs)
    const int bcol0 = ob * 192;            // Bt row base
    const int mh = (wave & 1) * 96;        // wave m-half
    const int gh = (wave >> 1) * 96;       // wave o-group half (32 outputs)
    const int lrow = lane & 15;
    const int quad = lane >> 4;
    const int coff = ((quad ^ ((lrow >> 1) & 3)) << 4);  // swizzled chunk col

    // per-thread staging addresses (3 A chunks + 3 B chunks per iter)
    const int r0 = tid >> 2, p0 = tid & 3;               // seg s=0
    const unsigned char* gA = A  + (size_t)(row0 + r0) * KTOT + p0 * 16;
    const signed char*   gB = Bt + (size_t)(bcol0 + r0) * KTOT + p0 * 16;

    i32x4 acc[6][6];                       // [mi][f], f = 2*d + q
#pragma unroll
    for (int mi = 0; mi < 6; ++mi)
#pragma unroll
        for (int f = 0; f < 6; ++f)
            acc[mi][f] = (i32x4){0, 0, 0, 0};

    // stage(buf, kb): 192x64 A and B tiles; LDS dest = uniform base + lane*16
    auto stage = [&](int buf, int kb) {
        signed char* AshP = &Ash[buf][0][0];
        signed char* BshP = &Bsh[buf][0][0];
#pragma unroll
        for (int s = 0; s < 3; ++s) {
            int seg = tid + 256 * s;
            __builtin_amdgcn_global_load_lds(
                (const __attribute__((address_space(1))) void*)
                    (gA + (size_t)(s * 64) * KTOT + kb),
                (__attribute__((address_space(3))) void*)(AshP + seg * 16),
                16, 0, 0);
        }
#pragma unroll
        for (int s = 0; s < 3; ++s) {
            int seg = tid + 256 * s;
            __builtin_amdgcn_global_load_lds(
                (const __attribute__((address_space(1))) void*)
                    (gB + (size_t)(s * 64) * KTOT + kb),
                (__attribute__((address_space(3))) void*)(BshP + seg * 16),
                16, 0, 0);
        }
    };

    // prologue: tile 0 into buffer 0
    stage(0, 0);
    __syncthreads();

    for (int kbi = 0; kbi < KTOT / 64; ++kbi) {
        const int cur = kbi & 1;
        if (kbi + 1 < KTOT / 64)
            stage(1 - cur, (kbi + 1) * 64);   // async prefetch into other buf

        i32x4 af[6], bf[6];
#pragma unroll
        for (int mi = 0; mi < 6; ++mi)
            af[mi] = *(const i32x4*)&Ash[cur][mh + mi * 16 + lrow][coff];
#pragma unroll
        for (int f = 0; f < 6; ++f)
            bf[f] = *(const i32x4*)&Bsh[cur][gh + f * 16 + lrow][coff];

#pragma unroll
        for (int mi = 0; mi < 6; ++mi)
#pragma unroll
            for (int f = 0; f < 6; ++f)
                acc[mi][f] = __builtin_amdgcn_mfma_i32_16x16x64_i8(
                    af[mi], bf[f], acc[mi][f], 0, 0, 0);

        __syncthreads();   // drains prefetch (vmcnt) + reads (lgkm) post-compute
    }

    // epilogue: C/D layout col=lane&15 (n), row=quad*4+reg (m).
#pragma unroll
    for (int mi = 0; mi < 6; ++mi) {
#pragma unroll
        for (int q = 0; q < 2; ++q) {
#pragma unroll
            for (int r = 0; r < 4; ++r) {
                int bt = row0 + mh + mi * 16 + quad * 4 + r;
                int o  = ob * 64 + (wave >> 1) * 32 + q * 16 + lrow;
                double pq = ((double)acc[mi][q][r]
                           + 256.0   * (double)acc[mi][2 + q][r]
                           + 65536.0 * (double)acc[mi][4 + q][r])
                          * (1.0 / 4194304.0);
                if (bt < MVAL) pot[(size_t)bt * O_ + o] = (float)pq;
            }
        }
    }
}

// ===========================================================================
// FALLBACK (round-1 direct conv) — only if ws_size too small
// ===========================================================================
__global__ void transpose_w(const float* __restrict__ w, float* __restrict__ wT) {
    int idx = blockIdx.x * 256 + threadIdx.x;
    if (idx >= O_ * S_) return;
    int o = idx >> 6, i = idx & 63;
    wT[i * O_ + o] = w[idx];
}

__global__ __launch_bounds__(256) void conv_kernel(
    const float* __restrict__ x, const float* __restrict__ wT,
    float* __restrict__ pot)
{
    const int b  = blockIdx.y;
    const int t0 = blockIdx.z * TT;
    const int o  = blockIdx.x * 256 + threadIdx.x;

    __shared__ __align__(16) float xsh[S_][WROW];
    for (int idx = threadIdx.x; idx < S_ * WROW; idx += 256) {
        int i = idx / WROW, m = idx - i * WROW;
        int t = t0 - KS_ + m;
        float v = 0.0f;
        if (t >= 0 && t < T_) v = x[(b * S_ + i) * T_ + t];
        xsh[i][m] = v;
    }
    __syncthreads();

    float acch[TT], accl[TT];
#pragma unroll
    for (int tl = 0; tl < TT; ++tl) { acch[tl] = 0.0f; accl[tl] = 0.0f; }

    for (int i = 0; i < S_; ++i) {
        float xw[WROW];
#pragma unroll
        for (int w4 = 0; w4 < WROW / 4; ++w4) {
            const float4 v = *reinterpret_cast<const float4*>(&xsh[i][w4 * 4]);
            xw[w4 * 4 + 0] = v.x; xw[w4 * 4 + 1] = v.y;
            xw[w4 * 4 + 2] = v.z; xw[w4 * 4 + 3] = v.w;
        }
        const float wv = wT[i * O_ + o];
#pragma unroll
        for (int j = 1; j < KS_; ++j) {
            float rise = (float)j * 0.0625f;
            float leak = -((float)j - wv * 16.0f) * 0.03125f + wv;
            float kv   = fmaxf(0.0f, fminf(rise, leak));
            float khi  = rintf(kv * 4096.0f) * 2.44140625e-4f;
            float klo  = kv - khi;
#pragma unroll
            for (int tl = 0; tl < TT; ++tl) {
                float xv = xw[tl + (KS_ - 1) - j];
                acch[tl] = fmaf(xv, khi, acch[tl]);
                accl[tl] = fmaf(xv, klo, accl[tl]);
            }
        }
    }
#pragma unroll
    for (int tl = 0; tl < TT; ++tl) {
        int t = t0 + tl;
        if (t < TP_) pot[((size_t)b * TP_ + t) * O_ + o] = acch[tl] + accl[tl];
    }
}

// ===========================================================================
// SCAN
// ===========================================================================
__global__ void scan_prep(const float* __restrict__ pot, unsigned char* __restrict__ code) {
    int idx = blockIdx.x * 256 + threadIdx.x;
    if (idx >= B_ * TP_ * N_) return;
    int n  = idx & (N_ - 1);
    int bt = idx >> 8;
    const float* p = pot + (size_t)bt * O_ + n;
    float best = p[0]; int bo = 0;
#pragma unroll
    for (int oc = 1; oc < OC_; ++oc) {
        float v = p[oc * N_];
        if (v > best) { best = v; bo = oc; } // strict > keeps FIRST max (argmax)
    }
    code[idx] = ((best + 16.0f) > 32.0f) ? (unsigned char)(bo + 1) : (unsigned char)0;
}

// Batched walk: each outer iteration loads 48 INDEPENDENT bytes (one vmcnt
// batch), then walks in registers; every iteration advances >= 48.
__global__ void scan_run(const unsigned char* __restrict__ code, float* __restrict__ out) {
    int idx = blockIdx.x * 256 + threadIdx.x;
    if (idx >= B_ * N_) return;
    int b = idx >> 8, n = idx & 255;
    const unsigned char* c = code + (size_t)b * TP_ * N_ + n;
    int t = 0;
    while (t < TP_) {
        unsigned char buf[KS_];
#pragma unroll
        for (int k = 0; k < KS_; ++k) {
            int tt = t + k;
            buf[k] = (tt < TP_) ? c[(size_t)tt * N_] : (unsigned char)0;
        }
        int adv = KS_;
#pragma unroll
        for (int k = 0; k < KS_; ++k) {
            if (buf[k]) {
                out[(((size_t)b * OC_ + (buf[k] - 1)) * N_ + n) * TP_ + (t + k)] = 1.0f;
                adv = k + KS_;
                break;
            }
        }
        t += adv;
    }
}

// ===========================================================================
extern "C" void kernel_launch(void* const* d_in, const int* in_sizes, int n_in,
                              void* d_out, int out_size, void* d_ws, size_t ws_size,
                              hipStream_t stream) {
    const float* x = (const float*)d_in[0];   // [16][1][64][512] binary
    const float* w = (const float*)d_in[1];   // [2560][64]
    float* out = (float*)d_out;               // [16][10][256][561]

    char* ws = (char*)d_ws;
    const size_t szA = (size_t)MPAD * KTOT;        //  27,721,728
    const size_t szB = (size_t)BROWS * KTOT;       //  23,592,960
    const size_t szP = (size_t)MVAL * O_ * 4;      //  91,914,240
    const size_t szC = (size_t)B_ * TP_ * N_;      //   2,297,856
    const size_t need = szA + szB + szP + szC;     // ~145.5 MB

    hipMemsetAsync(d_out, 0, (size_t)out_size * sizeof(float), stream);

    if (ws_size >= need) {
        unsigned char* Aim = (unsigned char*)ws;
        signed char* Bt    = (signed char*)(ws + szA);
        float* pot         = (float*)(ws + szA + szB);
        unsigned char* code = (unsigned char*)(ws + szA + szB + szP);

        prep_A8<<<(MPAD * KTOT / 4 + 255) / 256, 256, 0, stream>>>(x, Aim);
        prep_B8<<<(O_ * KTOT + 255) / 256, 256, 0, stream>>>(w, Bt);
        gemm_i8<<<dim3(NB, MPAD / 192), 256, 0, stream>>>(Aim, Bt, pot);
        scan_prep<<<(B_ * TP_ * N_ + 255) / 256, 256, 0, stream>>>(pot, code);
        scan_run<<<(B_ * N_ + 255) / 256, 256, 0, stream>>>(code, out);
    } else {
        // fallback: round-1 direct conv (needs ~95 MB)
        size_t pot_bytes  = (size_t)B_ * TP_ * O_ * sizeof(float);
        size_t code_bytes = (size_t)B_ * TP_ * N_;
        float* pot = (float*)ws;
        unsigned char* code = (unsigned char*)(ws + pot_bytes);
        float* wT = (float*)(ws + pot_bytes + code_bytes);

        transpose_w<<<(O_ * S_ + 255) / 256, 256, 0, stream>>>(w, wT);
        conv_kernel<<<dim3(O_ / 256, B_, (TP_ + TT - 1) / TT), 256, 0, stream>>>(x, wT, pot);
        scan_prep<<<(B_ * TP_ * N_ + 255) / 256, 256, 0, stream>>>(pot, code);
        scan_run<<<(B_ * N_ + 255) / 256, 256, 0, stream>>>(code, out);
    }
}

// Round 7
// 317.527 us; speedup vs baseline: 1.3291x; 1.3291x over previous
//
#include <hip/hip_runtime.h>

// Problem constants (from reference)
#define B_   16
#define OC_  10
#define N_   256
#define O_   2560   // OC_*N_
#define S_   64     // synapses
#define T_   512
#define KS_  48
#define TP_  561    // T + KS + 1
#define TT   24     // (fallback conv) time steps per thread
#define WROW 72     // (fallback conv) LDS row stride

// B-stationary GEMM constants
#define NOC   160           // o-chunks of 16 outputs
#define XROWS 624           // xT rows: t' + 48 - j + 1 range, zero-padded
#define XPITCH 80           // LDS pitch for xT rows (bank spread, 16B-aligned)
#define BPITCH 96           // row pitch for B (global AND LDS; 64 data + 32 pad)
#define JC    6             // j's staged per barrier

using i32x4 = __attribute__((ext_vector_type(4))) int;

// ===========================================================================
// prep_xb: x [16][64][512] f32 -> xb [16][512][64] bytes in {0,1}
// ===========================================================================
__global__ void prep_xb(const float* __restrict__ x, unsigned char* __restrict__ xb) {
    int idx = blockIdx.x * 256 + threadIdx.x;       // (b*64+i)*512 + t
    if (idx >= B_ * S_ * T_) return;
    int t = idx & 511;
    int bi = idx >> 9;
    int i = bi & 63, b = bi >> 6;
    xb[((size_t)(b * 512 + t) << 6) + i] = (x[idx] != 0.0f) ? 1 : 0;
}

// ===========================================================================
// prep_B8g: taps -> three signed base-256 digits (22-bit fixed point), into
// Bg[oc][j][row=d*16+ol][BPITCH], row bytes 0..63 = i.  Pad bytes pre-zeroed
// by memset.  All 3 digits of output o land in the SAME mfma lane.
// ===========================================================================
__global__ void prep_B8g(const float* __restrict__ w, signed char* __restrict__ Bg) {
    int idx = blockIdx.x * 256 + threadIdx.x;       // (o*48 + j)*64 + i
    if (idx >= O_ * KS_ * S_) return;
    int i = idx & 63;
    int oj = idx >> 6;
    int j = oj % KS_, o = oj / KS_;
    float wv = w[(o << 6) + i];
    float rise = (float)j * 0.0625f;
    float leak = -((float)j - wv * 16.0f) * 0.03125f + wv;
    float kv   = fmaxf(0.0f, fminf(rise, leak));     // in [0,1]
    int q  = (int)lrintf(kv * 4194304.0f);           // kv * 2^22
    int d0 = ((q + 128) & 255) - 128;                // [-128,127]
    int q1 = (q - d0) >> 8;
    int d1 = ((q1 + 128) & 255) - 128;               // [-128,127]
    int d2 = (q1 - d1) >> 8;                         // [0,64]
    int oc = o >> 4, ol = o & 15;
    size_t base = ((size_t)(oc * KS_ + j) * 48 + ol) * BPITCH + i;
    Bg[base]                 = (signed char)d0;
    Bg[base + 16 * BPITCH]   = (signed char)d1;
    Bg[base + 32 * BPITCH]   = (signed char)d2;
}

// ===========================================================================
// gemm_i8 (B-stationary): block = (oc, b).  x[b] lives in LDS for the whole
// kernel (time-transposed, zero-padded, XPITCH rows); only B streams, 6 j's
// (27.6 KB) per barrier vs 27*6*4 = 648 block-MFMAs.  K-order k'=j*64+i:
// A-frag for (t-tile, j) = one contiguous 16B row slice of xT -> no im2col.
// mfma_i32_16x16x64_i8, exact int32 accumulation, in-lane digit combine.
// ===========================================================================
__global__ __launch_bounds__(256, 2) void gemm_i8(
    const unsigned char* __restrict__ xb,   // [16][512][64]
    const signed char*  __restrict__ Bg,    // [NOC][48][48][BPITCH]
    float* __restrict__ pot)                // [B_*TP_][O_]
{
    __shared__ __align__(16) unsigned char xT[XROWS * XPITCH];   // 49,920 B
    __shared__ __align__(16) signed char  Bst[JC * 48 * BPITCH]; // 27,648 B

    const int tid  = threadIdx.x;
    const int lane = tid & 63;
    const int wave = tid >> 6;
    const int oc = blockIdx.x;             // 0..159
    const int b  = blockIdx.y;             // 0..15
    const int lrow = lane & 15;
    const int quad = lane >> 4;
    const int tw = wave * 144;             // wave m-base (t)

    // ---- zero xT, then load x[b] into rows 49..560 (row r <-> x[r-49]) ----
    for (int z = tid; z < XROWS * XPITCH / 16; z += 256)
        *(i32x4*)(xT + z * 16) = (i32x4){0, 0, 0, 0};
    __syncthreads();
    const unsigned char* xbb = xb + ((size_t)b << 15);   // 512*64 bytes
    for (int q = tid; q < 2048; q += 256) {              // 16-B chunks
        i32x4 v = *(const i32x4*)(xbb + q * 16);
        int t = q >> 2, p = q & 3;
        *(i32x4*)(xT + (49 + t) * XPITCH + p * 16) = v;
    }

    i32x4 acc[9][3];
#pragma unroll
    for (int mi = 0; mi < 9; ++mi)
#pragma unroll
        for (int f = 0; f < 3; ++f)
            acc[mi][f] = (i32x4){0, 0, 0, 0};

    __syncthreads();

    for (int jc = 0; jc < KS_; jc += JC) {
        // stage Bg[oc][jc..jc+JC) : JC*48 rows of BPITCH  (contiguous)
        {
            const signed char* src = Bg + ((size_t)oc * KS_ + jc) * 48 * BPITCH;
            signed char* dst = (signed char*)Bst;
            for (int c = tid; c < JC * 48 * BPITCH / 16; c += 256)
                __builtin_amdgcn_global_load_lds(
                    (const __attribute__((address_space(1))) void*)(src + c * 16),
                    (__attribute__((address_space(3))) void*)(dst + c * 16),
                    16, 0, 0);
        }
        __syncthreads();   // drains staging (vmcnt) before reads

#pragma unroll
        for (int jl = 0; jl < JC; ++jl) {
            const int j = jc + jl;
            i32x4 af[9], bf[3];
#pragma unroll
            for (int mi = 0; mi < 9; ++mi)
                af[mi] = *(const i32x4*)
                    (xT + (tw + mi * 16 + lrow + 48 - j) * XPITCH + quad * 16);
#pragma unroll
            for (int f = 0; f < 3; ++f)
                bf[f] = *(const i32x4*)
                    (Bst + (jl * 48 + f * 16 + lrow) * BPITCH + quad * 16);
#pragma unroll
            for (int mi = 0; mi < 9; ++mi)
#pragma unroll
                for (int f = 0; f < 3; ++f)
                    acc[mi][f] = __builtin_amdgcn_mfma_i32_16x16x64_i8(
                        af[mi], bf[f], acc[mi][f], 0, 0, 0);
        }
        __syncthreads();   // all waves done reading Bst before next stage
    }

    // ---- epilogue: C/D col=lane&15 (ol), row=quad*4+r (t); digits in-lane --
    const size_t potb = (size_t)b * TP_;
#pragma unroll
    for (int mi = 0; mi < 9; ++mi) {
#pragma unroll
        for (int r = 0; r < 4; ++r) {
            int t = tw + mi * 16 + quad * 4 + r;
            if (t < TP_) {
                double pq = ((double)acc[mi][0][r]
                           + 256.0   * (double)acc[mi][1][r]
                           + 65536.0 * (double)acc[mi][2][r])
                          * (1.0 / 4194304.0);
                pot[(potb + t) * O_ + oc * 16 + lrow] = (float)pq;
            }
        }
    }
}

// ===========================================================================
// FALLBACK (round-1 direct conv) — only if ws_size too small
// ===========================================================================
__global__ void transpose_w(const float* __restrict__ w, float* __restrict__ wT) {
    int idx = blockIdx.x * 256 + threadIdx.x;
    if (idx >= O_ * S_) return;
    int o = idx >> 6, i = idx & 63;
    wT[i * O_ + o] = w[idx];
}

__global__ __launch_bounds__(256) void conv_kernel(
    const float* __restrict__ x, const float* __restrict__ wT,
    float* __restrict__ pot)
{
    const int b  = blockIdx.y;
    const int t0 = blockIdx.z * TT;
    const int o  = blockIdx.x * 256 + threadIdx.x;

    __shared__ __align__(16) float xsh[S_][WROW];
    for (int idx = threadIdx.x; idx < S_ * WROW; idx += 256) {
        int i = idx / WROW, m = idx - i * WROW;
        int t = t0 - KS_ + m;
        float v = 0.0f;
        if (t >= 0 && t < T_) v = x[(b * S_ + i) * T_ + t];
        xsh[i][m] = v;
    }
    __syncthreads();

    float acch[TT], accl[TT];
#pragma unroll
    for (int tl = 0; tl < TT; ++tl) { acch[tl] = 0.0f; accl[tl] = 0.0f; }

    for (int i = 0; i < S_; ++i) {
        float xw[WROW];
#pragma unroll
        for (int w4 = 0; w4 < WROW / 4; ++w4) {
            const float4 v = *reinterpret_cast<const float4*>(&xsh[i][w4 * 4]);
            xw[w4 * 4 + 0] = v.x; xw[w4 * 4 + 1] = v.y;
            xw[w4 * 4 + 2] = v.z; xw[w4 * 4 + 3] = v.w;
        }
        const float wv = wT[i * O_ + o];
#pragma unroll
        for (int j = 1; j < KS_; ++j) {
            float rise = (float)j * 0.0625f;
            float leak = -((float)j - wv * 16.0f) * 0.03125f + wv;
            float kv   = fmaxf(0.0f, fminf(rise, leak));
            float khi  = rintf(kv * 4096.0f) * 2.44140625e-4f;
            float klo  = kv - khi;
#pragma unroll
            for (int tl = 0; tl < TT; ++tl) {
                float xv = xw[tl + (KS_ - 1) - j];
                acch[tl] = fmaf(xv, khi, acch[tl]);
                accl[tl] = fmaf(xv, klo, accl[tl]);
            }
        }
    }
#pragma unroll
    for (int tl = 0; tl < TT; ++tl) {
        int t = t0 + tl;
        if (t < TP_) pot[((size_t)b * TP_ + t) * O_ + o] = acch[tl] + accl[tl];
    }
}

// ===========================================================================
// SCAN
// ===========================================================================
__global__ void scan_prep(const float* __restrict__ pot, unsigned char* __restrict__ code) {
    int idx = blockIdx.x * 256 + threadIdx.x;
    if (idx >= B_ * TP_ * N_) return;
    int n  = idx & (N_ - 1);
    int bt = idx >> 8;
    const float* p = pot + (size_t)bt * O_ + n;
    float best = p[0]; int bo = 0;
#pragma unroll
    for (int oc = 1; oc < OC_; ++oc) {
        float v = p[oc * N_];
        if (v > best) { best = v; bo = oc; } // strict > keeps FIRST max (argmax)
    }
    code[idx] = ((best + 16.0f) > 32.0f) ? (unsigned char)(bo + 1) : (unsigned char)0;
}

// Batched walk: each outer iteration loads 48 INDEPENDENT bytes (one vmcnt
// batch), then walks in registers; every iteration advances >= 48.
__global__ void scan_run(const unsigned char* __restrict__ code, float* __restrict__ out) {
    int idx = blockIdx.x * 256 + threadIdx.x;
    if (idx >= B_ * N_) return;
    int b = idx >> 8, n = idx & 255;
    const unsigned char* c = code + (size_t)b * TP_ * N_ + n;
    int t = 0;
    while (t < TP_) {
        unsigned char buf[KS_];
#pragma unroll
        for (int k = 0; k < KS_; ++k) {
            int tt = t + k;
            buf[k] = (tt < TP_) ? c[(size_t)tt * N_] : (unsigned char)0;
        }
        int adv = KS_;
#pragma unroll
        for (int k = 0; k < KS_; ++k) {
            if (buf[k]) {
                out[(((size_t)b * OC_ + (buf[k] - 1)) * N_ + n) * TP_ + (t + k)] = 1.0f;
                adv = k + KS_;
                break;
            }
        }
        t += adv;
    }
}

// ===========================================================================
extern "C" void kernel_launch(void* const* d_in, const int* in_sizes, int n_in,
                              void* d_out, int out_size, void* d_ws, size_t ws_size,
                              hipStream_t stream) {
    const float* x = (const float*)d_in[0];   // [16][1][64][512] binary
    const float* w = (const float*)d_in[1];   // [2560][64]
    float* out = (float*)d_out;               // [16][10][256][561]

    char* ws = (char*)d_ws;
    const size_t szX = (size_t)B_ * T_ * S_;                    //     524,288
    const size_t szB = (size_t)NOC * KS_ * 48 * BPITCH;         //  35,389,440
    const size_t szP = (size_t)B_ * TP_ * O_ * 4;               //  91,914,240
    const size_t szC = (size_t)B_ * TP_ * N_;                   //   2,297,856
    const size_t need = szX + szB + szP + szC;                  // ~130.1 MB

    hipMemsetAsync(d_out, 0, (size_t)out_size * sizeof(float), stream);

    if (ws_size >= need) {
        unsigned char* xb  = (unsigned char*)ws;
        signed char* Bg    = (signed char*)(ws + szX);
        float* pot         = (float*)(ws + szX + szB);
        unsigned char* code = (unsigned char*)(ws + szX + szB + szP);

        hipMemsetAsync(Bg, 0, szB, stream);   // pad bytes of B rows
        prep_xb<<<(B_ * S_ * T_ + 255) / 256, 256, 0, stream>>>(x, xb);
        prep_B8g<<<(O_ * KS_ * S_ + 255) / 256, 256, 0, stream>>>(w, Bg);
        gemm_i8<<<dim3(NOC, B_), 256, 0, stream>>>(xb, Bg, pot);
        scan_prep<<<(B_ * TP_ * N_ + 255) / 256, 256, 0, stream>>>(pot, code);
        scan_run<<<(B_ * N_ + 255) / 256, 256, 0, stream>>>(code, out);
    } else {
        // fallback: round-1 direct conv (needs ~95 MB)
        size_t pot_bytes  = (size_t)B_ * TP_ * O_ * sizeof(float);
        size_t code_bytes = (size_t)B_ * TP_ * N_;
        float* pot = (float*)ws;
        unsigned char* code = (unsigned char*)(ws + pot_bytes);
        float* wT = (float*)(ws + pot_bytes + code_bytes);

        transpose_w<<<(O_ * S_ + 255) / 256, 256, 0, stream>>>(w, wT);
        conv_kernel<<<dim3(O_ / 256, B_, (TP_ + TT - 1) / TT), 256, 0, stream>>>(x, wT, pot);
        scan_prep<<<(B_ * TP_ * N_ + 255) / 256, 256, 0, stream>>>(pot, code);
        scan_run<<<(B_ * N_ + 255) / 256, 256, 0, stream>>>(code, out);
    }
}